// Round 15
// baseline (152.147 us; speedup 1.0000x reference)
//
#include <hip/hip_runtime.h>
#include <hip/hip_bf16.h>

typedef __attribute__((ext_vector_type(8))) short short8;
typedef __attribute__((ext_vector_type(4))) float f32x4;

#define NT 65536

__device__ __forceinline__ unsigned short f2bf(float f) {
    union { float f; unsigned int u; } v; v.f = f;
    unsigned int u = v.u;
    unsigned int r = (u + 0x7fffu + ((u >> 16) & 1u)) >> 16;  // RNE
    return (unsigned short)r;
}

__device__ __forceinline__ unsigned int cvt_pk_bf16(float lo, float hi) {
    unsigned int r;
    asm("v_cvt_pk_bf16_f32 %0, %1, %2" : "=v"(r) : "v"(lo), "v"(hi));
    return r;
}

// ---------------- prep (all 3 sources): bf16 B panel + per-k params ----------------
// Panel row n: k16=n>>5, typ=(n>>4)&1, r=n&15 -> k=k16*16+r; typ0=w, typ1=beta.
// prm per source (5*256 f32): [0:256)=||w_k||^2, [256)=gam^2, [512)=eta^2, [768)=alpha, [1024)=sig^2
__global__ void prep_kernel(const float* __restrict__ w0, const float* __restrict__ b0,
                            const float* __restrict__ a0, const float* __restrict__ s0,
                            const float* __restrict__ e0, const float* __restrict__ g0,
                            const float* __restrict__ w1, const float* __restrict__ b1,
                            const float* __restrict__ a1, const float* __restrict__ s1,
                            const float* __restrict__ e1, const float* __restrict__ g1,
                            const float* __restrict__ w2, const float* __restrict__ b2,
                            const float* __restrict__ a2, const float* __restrict__ s2,
                            const float* __restrict__ e2, const float* __restrict__ g2,
                            unsigned short* __restrict__ bc, float* __restrict__ prmAll) {
    __shared__ float red[2];
    const int bx = blockIdx.x;
    const int s = bx >> 9;            // 0..2
    const int n = bx & 511;           // panel row
    const int P = 512 >> s;
    const float* w   = (s == 0) ? w0 : ((s == 1) ? w1 : w2);
    const float* bet = (s == 0) ? b0 : ((s == 1) ? b1 : b2);
    const float* alp = (s == 0) ? a0 : ((s == 1) ? a1 : a2);
    const float* sig = (s == 0) ? s0 : ((s == 1) ? s1 : s2);
    const float* eta = (s == 0) ? e0 : ((s == 1) ? e1 : e2);
    const float* gam = (s == 0) ? g0 : ((s == 1) ? g1 : g2);
    unsigned short* dstb = bc + ((s == 0) ? 0 : ((s == 1) ? (512 * 512) : (512 * 512 + 512 * 256)));
    float* prm = prmAll + 1280 * s;

    const int tid = threadIdx.x;      // 128
    const int k16 = n >> 5;
    const int typ = (n >> 4) & 1;
    const int k = k16 * 16 + (n & 15);
    const bool isw = (typ == 0);
    const float* src = (isw ? w : bet) + (size_t)k * P;
    unsigned short* dst = dstb + (size_t)n * P;
    float ss = 0.f;
    for (int c = tid; c < P; c += 128) {
        float f = src[c];
        dst[c] = f2bf(f);
        if (isw) ss += f * f;
    }
#pragma unroll
    for (int m = 1; m < 64; m <<= 1) ss += __shfl_xor(ss, m);
    if ((tid & 63) == 0) red[tid >> 6] = ss;
    __syncthreads();
    if (isw && tid == 0) prm[k] = red[0] + red[1];
    if (n == 0) {
        for (int kk = tid; kk < 256; kk += 128) {
            float g = gam[kk], e = eta[kk];
            prm[256 + kk]  = g * g;
            prm[512 + kk]  = e * e;
            prm[768 + kk]  = alp[kk];
            prm[1024 + kk] = sig[kk] * sig[kk];
        }
    }
}

// ---------------- fused per-source: R4 body + (512,1) bounds + WIN=4 ----------------
// grid 256 x 512 thr (8 waves). h = bx&1 (k-half), rg = bx>>1 (0..127).
// Block processes 8 row-tiles of 64 rows (tiles rg + 128*tt). Wave wv owns k16 = h*8+wv
// (16 k's = w-strip + beta-strip); Bf[2][KS] register-resident (256-reg budget at
// launch_bounds(512,1) - LDS already caps residency at 1 block/CU, so the old (512,2)
// bound only throttled VGPRs and forced per-MFMA L2 remat of Bf = the 1400cy/step stall).
// A staged fp32->bf16 into double-buffered LDS; granule loads issued WIN=4 steps ahead
// of cvt+ds_write (2x the R4 issue->consume distance). LDS 16B slots XOR-swizzled:
// phys = slot^(row&7). Swapped MFMA mfma(Bf, af): k lane-local -> register epilogue.
template<int P>
__global__ __launch_bounds__(512, 1)
void fused_src(const float* __restrict__ x, const unsigned short* __restrict__ Bc,
               const float* __restrict__ prm, float* __restrict__ pws) {
    constexpr int KS  = P / 32;              // MFMA k-steps per tile (16/8/4)
    constexpr int IST = P / 64;              // staging granules per thread per tile (8/4/2)
    constexpr int WIN = (P == 128) ? 2 : 4;  // load->consume distance (reg window)

    __shared__ unsigned short As[2][64 * P];
    __shared__ float xn2s[2][64];
    __shared__ float part[8][64][3];

    const int bx = blockIdx.x;
    const int h  = bx & 1;
    const int rg = bx >> 1;                  // 0..127
    const int tid = threadIdx.x, lane = tid & 63, wv = tid >> 6;
    const int l15 = lane & 15, l4 = lane >> 4;
    const int k16 = h * 8 + wv;

    // ---- resident B fragments (A-operand layout: row = strip-row l15, k-off = 8*l4) ----
    short8 Bf[2][KS];
#pragma unroll
    for (int st = 0; st < 2; st++)
#pragma unroll
        for (int ks = 0; ks < KS; ks++)
            Bf[st][ks] = *(const short8*)(Bc + (size_t)(k16 * 32 + st * 16 + l15) * P + ks * 32 + l4 * 8);

    // ---- per-lane params for k = k16*16 + 4*l4 + j ----
    const int kb = k16 * 16 + 4 * l4;
    const f32x4 wn2 = *(const f32x4*)(prm + kb);
    const f32x4 g2  = *(const f32x4*)(prm + 256 + kb);
    const f32x4 hv  = *(const f32x4*)(prm + 512 + kb);
    const f32x4 alv = *(const f32x4*)(prm + 768 + kb);
    const f32x4 s2v = *(const f32x4*)(prm + 1024 + kb);

    // staging geometry: thread t -> row = t>>3 (0..63), slots (t&7) + 8*i, i < IST
    const int srow = tid >> 3;
    const int ssl0 = tid & 7;

    // ---- prologue: stage tile 0 into buf 0 ----
    {
        const int row0 = rg * 64;
        float4 pa[IST], pb[IST];
#pragma unroll
        for (int i = 0; i < IST; i++) {
            const float* gp = x + (size_t)(row0 + srow) * P + (ssl0 + 8 * i) * 8;
            pa[i] = *(const float4*)(gp);
            pb[i] = *(const float4*)(gp + 4);
        }
        float ssacc = 0.f;
#pragma unroll
        for (int i = 0; i < IST; i++) {
            float4 a0 = pa[i], a1 = pb[i];
            ssacc += a0.x*a0.x + a0.y*a0.y + a0.z*a0.z + a0.w*a0.w
                   + a1.x*a1.x + a1.y*a1.y + a1.z*a1.z + a1.w*a1.w;
            uint4 pk = { cvt_pk_bf16(a0.x, a0.y), cvt_pk_bf16(a0.z, a0.w),
                         cvt_pk_bf16(a1.x, a1.y), cvt_pk_bf16(a1.z, a1.w) };
            const int slot = ssl0 + 8 * i;
            *(uint4*)(&As[0][srow * P + ((slot ^ (srow & 7)) << 3)]) = pk;
        }
        ssacc += __shfl_xor(ssacc, 1);
        ssacc += __shfl_xor(ssacc, 2);
        ssacc += __shfl_xor(ssacc, 4);
        if (ssl0 == 0) xn2s[0][srow] = ssacc;
    }
    __syncthreads();

    int buf = 0;
    for (int tt = 0; tt < 8; tt++) {
        const int tile = rg + 128 * tt;
        const int row0 = tile * 64;
        const bool more = (tt < 7);
        const int nrow0 = (tile + 128) * 64;

        f32x4 acc[2][4];
#pragma unroll
        for (int st = 0; st < 2; st++)
#pragma unroll
            for (int rf = 0; rf < 4; rf++) acc[st][rf] = (f32x4){0.f, 0.f, 0.f, 0.f};

        float4 gfa[WIN], gfb[WIN];
        float ssacc = 0.f;

#pragma unroll
        for (int ks = 0; ks < KS; ks++) {
            // consume granule ks-WIN (cvt + swizzled ds_write into buf^1, ||x||^2 partial)
            if (more && ks >= WIN && (ks - WIN) < IST) {
                const int i = ks - WIN;
                float4 a0 = gfa[i % WIN], a1 = gfb[i % WIN];
                ssacc += a0.x*a0.x + a0.y*a0.y + a0.z*a0.z + a0.w*a0.w
                       + a1.x*a1.x + a1.y*a1.y + a1.z*a1.z + a1.w*a1.w;
                uint4 pk = { cvt_pk_bf16(a0.x, a0.y), cvt_pk_bf16(a0.z, a0.w),
                             cvt_pk_bf16(a1.x, a1.y), cvt_pk_bf16(a1.z, a1.w) };
                const int slot = ssl0 + 8 * i;
                *(uint4*)(&As[buf ^ 1][srow * P + ((slot ^ (srow & 7)) << 3)]) = pk;
            }
            // issue granule ks loads for next tile
            if (more && ks < IST) {
                const float* gp = x + (size_t)(nrow0 + srow) * P + (ssl0 + 8 * ks) * 8;
                gfa[ks % WIN] = *(const float4*)(gp);
                gfb[ks % WIN] = *(const float4*)(gp + 4);
            }
            // fragments + MFMA (A-operand = resident B, B-operand = x frag)
            short8 af[4];
#pragma unroll
            for (int rf = 0; rf < 4; rf++) {
                const int row = 16 * rf + l15;
                af[rf] = *(const short8*)(&As[buf][row * P + (((ks * 4 + l4) ^ (row & 7)) << 3)]);
            }
#pragma unroll
            for (int rf = 0; rf < 4; rf++) {
                acc[0][rf] = __builtin_amdgcn_mfma_f32_16x16x32_bf16(Bf[0][ks], af[rf], acc[0][rf], 0, 0, 0);
                acc[1][rf] = __builtin_amdgcn_mfma_f32_16x16x32_bf16(Bf[1][ks], af[rf], acc[1][rf], 0, 0, 0);
            }
        }

        // tail: consume remaining granules (only when KS-WIN < IST)
        if (more) {
#pragma unroll
            for (int i = (KS - WIN < 0 ? 0 : KS - WIN); i < IST; i++) {
                float4 a0 = gfa[i % WIN], a1 = gfb[i % WIN];
                ssacc += a0.x*a0.x + a0.y*a0.y + a0.z*a0.z + a0.w*a0.w
                       + a1.x*a1.x + a1.y*a1.y + a1.z*a1.z + a1.w*a1.w;
                uint4 pk = { cvt_pk_bf16(a0.x, a0.y), cvt_pk_bf16(a0.z, a0.w),
                             cvt_pk_bf16(a1.x, a1.y), cvt_pk_bf16(a1.z, a1.w) };
                const int slot = ssl0 + 8 * i;
                *(uint4*)(&As[buf ^ 1][srow * P + ((slot ^ (srow & 7)) << 3)]) = pk;
            }
            ssacc += __shfl_xor(ssacc, 1);
            ssacc += __shfl_xor(ssacc, 2);
            ssacc += __shfl_xor(ssacc, 4);
            if (ssl0 == 0) xn2s[buf ^ 1][srow] = ssacc;
        }
        __syncthreads();   // sync1: accs final, next tile staged

        // epilogue: lane holds x-row = 16rf + l15 (col), k = kb + j (row/register)
#pragma unroll
        for (int rf = 0; rf < 4; rf++) {
            const int row = 16 * rf + l15;
            const float xv = xn2s[buf][row];
            float hs = 0.f, ms = 0.f, gs = 0.f;
#pragma unroll
            for (int j = 0; j < 4; j++) {
                float d2 = xv - 2.f * acc[0][rf][j] + wn2[j];
                float a  = __expf(-g2[j] * d2);
                float ah = a * hv[j];
                hs += ah;
                ms += (acc[1][rf][j] + alv[j]) * ah;
                gs += s2v[j] * ah * ah;
            }
            hs += __shfl_xor(hs, 16); hs += __shfl_xor(hs, 32);
            ms += __shfl_xor(ms, 16); ms += __shfl_xor(ms, 32);
            gs += __shfl_xor(gs, 16); gs += __shfl_xor(gs, 32);
            if (l4 == 0) { part[wv][row][0] = hs; part[wv][row][1] = ms; part[wv][row][2] = gs; }
        }
        __syncthreads();
        if (tid < 192) {
            const int v = tid >> 6, r = tid & 63;
            float sum = 0.f;
#pragma unroll
            for (int w8 = 0; w8 < 8; w8++) sum += part[w8][r][v];
            pws[(size_t)(h * 3 + v) * NT + row0 + r] = sum;
        }
        __syncthreads();
        buf ^= 1;
    }
}

// ---------------- combine: all outputs from 2 h-partials per source ----------------
__global__ void combine_kernel(const float* __restrict__ pws,
                               const float* __restrict__ d0, const float* __restrict__ d1,
                               const float* __restrict__ d2, float* __restrict__ out) {
    const int t = blockIdx.x * 256 + threadIdx.x;
    float mux[3], s2x[3], hx[3];
#pragma unroll
    for (int s = 0; s < 3; s++) {
        const float* b = pws + (size_t)s * 6 * NT;
        const float hh = b[t] + b[(size_t)3 * NT + t];
        const float mm = b[(size_t)1 * NT + t] + b[(size_t)4 * NT + t];
        const float gg = b[(size_t)2 * NT + t] + b[(size_t)5 * NT + t];
        mux[s] = mm / hh; s2x[s] = gg / (hh * hh); hx[s] = hh;
        out[(size_t)s * NT + t]       = mux[s];
        out[(size_t)(4 + s) * NT + t] = s2x[s];
        out[(size_t)(8 + s) * NT + t] = hh;
    }
    const float sd0 = 1.f / (1.f + __expf(-d0[0]));
    const float sd1 = 1.f / (1.f + __expf(-d1[0]));
    const float sd2 = 1.f / (1.f + __expf(-d2[0]));
    const float c0 = hx[0] * sd0, c1 = hx[1] * sd1, c2 = hx[2] * sd2;
    const float den = c0 + c1 + c2;
    const float muc = mux[0] * c0 + mux[1] * c1 + mux[2] * c2;
    const float sgc = s2x[0] * c0 * c0 + s2x[1] * c1 * c1 + s2x[2] * c2 * c2;
    out[(size_t)3 * NT + t]  = muc / den;
    out[(size_t)7 * NT + t]  = sgc / (den * den);
    out[(size_t)11 * NT + t] = den;
}

extern "C" void kernel_launch(void* const* d_in, const int* in_sizes, int n_in,
                              void* d_out, int out_size, void* d_ws, size_t ws_size,
                              hipStream_t stream) {
    // input order per source i: x=8i, alpha=8i+1, beta=8i+2, sig=8i+3, eta=8i+4, gam=8i+5, w=8i+6, disc=8i+7
    const float* x0 = (const float*)d_in[0];
    const float* x1 = (const float*)d_in[8];
    const float* x2 = (const float*)d_in[16];

    unsigned short* bc = (unsigned short*)d_ws;                  // 512*(512+256+128) ushorts = 917504 B
    float* prmAll = (float*)((char*)d_ws + 917504);              // 3*1280 floats = 15360 B
    float* pws    = (float*)((char*)d_ws + 917504 + 15360);      // 18*NT floats = 4.72 MB
    float* out = (float*)d_out;

    prep_kernel<<<1536, 128, 0, stream>>>(
        (const float*)d_in[6],  (const float*)d_in[2],  (const float*)d_in[1],
        (const float*)d_in[3],  (const float*)d_in[4],  (const float*)d_in[5],
        (const float*)d_in[14], (const float*)d_in[10], (const float*)d_in[9],
        (const float*)d_in[11], (const float*)d_in[12], (const float*)d_in[13],
        (const float*)d_in[22], (const float*)d_in[18], (const float*)d_in[17],
        (const float*)d_in[19], (const float*)d_in[20], (const float*)d_in[21],
        bc, prmAll);

    const size_t bcoff1 = 512 * 512, bcoff2 = 512 * 512 + 512 * 256;
    fused_src<512><<<256, 512, 0, stream>>>(x0, bc,          prmAll,        pws);
    fused_src<256><<<256, 512, 0, stream>>>(x1, bc + bcoff1, prmAll + 1280, pws + (size_t)6 * NT);
    fused_src<128><<<256, 512, 0, stream>>>(x2, bc + bcoff2, prmAll + 2560, pws + (size_t)12 * NT);
    combine_kernel<<<256, 256, 0, stream>>>(pws, (const float*)d_in[7], (const float*)d_in[15],
                                            (const float*)d_in[23], out);
}

// Round 16
// 129.547 us; speedup vs baseline: 1.1745x; 1.1745x over previous
//
#include <hip/hip_runtime.h>
#include <hip/hip_bf16.h>

typedef __attribute__((ext_vector_type(8))) short short8;
typedef __attribute__((ext_vector_type(4))) float f32x4;

#define NT 65536

__device__ __forceinline__ unsigned short f2bf(float f) {
    union { float f; unsigned int u; } v; v.f = f;
    unsigned int u = v.u;
    unsigned int r = (u + 0x7fffu + ((u >> 16) & 1u)) >> 16;  // RNE
    return (unsigned short)r;
}

__device__ __forceinline__ unsigned int cvt_pk_bf16(float lo, float hi) {
    unsigned int r;
    asm("v_cvt_pk_bf16_f32 %0, %1, %2" : "=v"(r) : "v"(lo), "v"(hi));
    return r;
}

// ---------------- prep (all 3 sources): bf16 B panel + per-k params ----------------
// Panel row n: k16=n>>5, typ=(n>>4)&1, r=n&15 -> k=k16*16+r; typ0=w, typ1=beta.
// prm per source (5*256 f32): [0:256)=||w_k||^2, [256)=gam^2, [512)=eta^2, [768)=alpha, [1024)=sig^2
__global__ void prep_kernel(const float* __restrict__ w0, const float* __restrict__ b0,
                            const float* __restrict__ a0, const float* __restrict__ s0,
                            const float* __restrict__ e0, const float* __restrict__ g0,
                            const float* __restrict__ w1, const float* __restrict__ b1,
                            const float* __restrict__ a1, const float* __restrict__ s1,
                            const float* __restrict__ e1, const float* __restrict__ g1,
                            const float* __restrict__ w2, const float* __restrict__ b2,
                            const float* __restrict__ a2, const float* __restrict__ s2,
                            const float* __restrict__ e2, const float* __restrict__ g2,
                            unsigned short* __restrict__ bc, float* __restrict__ prmAll) {
    __shared__ float red[2];
    const int bx = blockIdx.x;
    const int s = bx >> 9;            // 0..2
    const int n = bx & 511;           // panel row
    const int P = 512 >> s;
    const float* w   = (s == 0) ? w0 : ((s == 1) ? w1 : w2);
    const float* bet = (s == 0) ? b0 : ((s == 1) ? b1 : b2);
    const float* alp = (s == 0) ? a0 : ((s == 1) ? a1 : a2);
    const float* sig = (s == 0) ? s0 : ((s == 1) ? s1 : s2);
    const float* eta = (s == 0) ? e0 : ((s == 1) ? e1 : e2);
    const float* gam = (s == 0) ? g0 : ((s == 1) ? g1 : g2);
    unsigned short* dstb = bc + ((s == 0) ? 0 : ((s == 1) ? (512 * 512) : (512 * 512 + 512 * 256)));
    float* prm = prmAll + 1280 * s;

    const int tid = threadIdx.x;      // 128
    const int k16 = n >> 5;
    const int typ = (n >> 4) & 1;
    const int k = k16 * 16 + (n & 15);
    const bool isw = (typ == 0);
    const float* src = (isw ? w : bet) + (size_t)k * P;
    unsigned short* dst = dstb + (size_t)n * P;
    float ss = 0.f;
    for (int c = tid; c < P; c += 128) {
        float f = src[c];
        dst[c] = f2bf(f);
        if (isw) ss += f * f;
    }
#pragma unroll
    for (int m = 1; m < 64; m <<= 1) ss += __shfl_xor(ss, m);
    if ((tid & 63) == 0) red[tid >> 6] = ss;
    __syncthreads();
    if (isw && tid == 0) prm[k] = red[0] + red[1];
    if (n == 0) {
        for (int kk = tid; kk < 256; kk += 128) {
            float g = gam[kk], e = eta[kk];
            prm[256 + kk]  = g * g;
            prm[512 + kk]  = e * e;
            prm[768 + kk]  = alp[kk];
            prm[1024 + kk] = sig[kk] * sig[kk];
        }
    }
}

// ======== s0 kernel: R4's fused_src VERBATIM (measured 74.7us at P=512) ========
// grid 256 x 512 thr (8 waves). h = bx&1 (k-half), rg = bx>>1.
// Block processes 8 row-tiles of 64 rows (tiles rg + 128*tt). Wave wv owns k16 = h*8+wv.
// A staged fp32->bf16 into double-buffered LDS; granule loads issued WIN steps ahead.
// LDS 16B slots XOR-swizzled: phys = slot^(row&7). Swapped MFMA: k lane-local epilogue.
template<int P>
__global__ __launch_bounds__(512, 2)
void fused_s0(const float* __restrict__ x, const unsigned short* __restrict__ Bc,
              const float* __restrict__ prm, float* __restrict__ pws) {
    constexpr int KS  = P / 32;
    constexpr int IST = P / 64;
    constexpr int WIN = (P == 256) ? 4 : 2;
    __shared__ unsigned short As[2][64 * P];
    __shared__ float part[8][64][3];
    __shared__ float xn2s[2][64];

    const int bx = blockIdx.x;
    const int h  = bx & 1;
    const int rg = bx >> 1;
    const int tid = threadIdx.x, lane = tid & 63, wv = tid >> 6;
    const int l15 = lane & 15, l4 = lane >> 4;
    const int k16 = h * 8 + wv;

    short8 Bf[2][KS];
#pragma unroll
    for (int st = 0; st < 2; st++)
#pragma unroll
        for (int ks = 0; ks < KS; ks++)
            Bf[st][ks] = *(const short8*)(Bc + (size_t)(k16 * 32 + st * 16 + l15) * P + ks * 32 + l4 * 8);

    const int kb = k16 * 16 + 4 * l4;
    const f32x4 wn2 = *(const f32x4*)(prm + kb);
    const f32x4 g2  = *(const f32x4*)(prm + 256 + kb);
    const f32x4 hv  = *(const f32x4*)(prm + 512 + kb);
    const f32x4 alv = *(const f32x4*)(prm + 768 + kb);
    const f32x4 s2v = *(const f32x4*)(prm + 1024 + kb);

    const int srow = tid >> 3;
    const int ssl0 = tid & 7;

    {
        const int row0 = rg * 64;
        float4 pa[IST], pb[IST];
#pragma unroll
        for (int i = 0; i < IST; i++) {
            const float* gp = x + (size_t)(row0 + srow) * P + (ssl0 + 8 * i) * 8;
            pa[i] = *(const float4*)(gp);
            pb[i] = *(const float4*)(gp + 4);
        }
        float ssacc = 0.f;
#pragma unroll
        for (int i = 0; i < IST; i++) {
            float4 a0 = pa[i], a1 = pb[i];
            ssacc += a0.x*a0.x + a0.y*a0.y + a0.z*a0.z + a0.w*a0.w
                   + a1.x*a1.x + a1.y*a1.y + a1.z*a1.z + a1.w*a1.w;
            uint4 pk = { cvt_pk_bf16(a0.x, a0.y), cvt_pk_bf16(a0.z, a0.w),
                         cvt_pk_bf16(a1.x, a1.y), cvt_pk_bf16(a1.z, a1.w) };
            const int slot = ssl0 + 8 * i;
            *(uint4*)(&As[0][srow * P + ((slot ^ (srow & 7)) << 3)]) = pk;
        }
        ssacc += __shfl_xor(ssacc, 1);
        ssacc += __shfl_xor(ssacc, 2);
        ssacc += __shfl_xor(ssacc, 4);
        if (ssl0 == 0) xn2s[0][srow] = ssacc;
    }
    __syncthreads();

    int buf = 0;
    for (int tt = 0; tt < 8; tt++) {
        const int tile = rg + 128 * tt;
        const int row0 = tile * 64;
        const bool more = (tt < 7);
        const int nrow0 = (tile + 128) * 64;

        f32x4 acc[2][4];
#pragma unroll
        for (int st = 0; st < 2; st++)
#pragma unroll
            for (int rf = 0; rf < 4; rf++) acc[st][rf] = (f32x4){0.f, 0.f, 0.f, 0.f};

        float4 gfa[WIN], gfb[WIN];
        float ssacc = 0.f;

#pragma unroll
        for (int ks = 0; ks < KS; ks++) {
            if (more && ks >= WIN && (ks - WIN) < IST) {
                const int i = ks - WIN;
                float4 a0 = gfa[i % WIN], a1 = gfb[i % WIN];
                ssacc += a0.x*a0.x + a0.y*a0.y + a0.z*a0.z + a0.w*a0.w
                       + a1.x*a1.x + a1.y*a1.y + a1.z*a1.z + a1.w*a1.w;
                uint4 pk = { cvt_pk_bf16(a0.x, a0.y), cvt_pk_bf16(a0.z, a0.w),
                             cvt_pk_bf16(a1.x, a1.y), cvt_pk_bf16(a1.z, a1.w) };
                const int slot = ssl0 + 8 * i;
                *(uint4*)(&As[buf ^ 1][srow * P + ((slot ^ (srow & 7)) << 3)]) = pk;
            }
            if (more && ks < IST) {
                const float* gp = x + (size_t)(nrow0 + srow) * P + (ssl0 + 8 * ks) * 8;
                gfa[ks % WIN] = *(const float4*)(gp);
                gfb[ks % WIN] = *(const float4*)(gp + 4);
            }
            short8 af[4];
#pragma unroll
            for (int rf = 0; rf < 4; rf++) {
                const int row = 16 * rf + l15;
                af[rf] = *(const short8*)(&As[buf][row * P + (((ks * 4 + l4) ^ (row & 7)) << 3)]);
            }
#pragma unroll
            for (int rf = 0; rf < 4; rf++) {
                acc[0][rf] = __builtin_amdgcn_mfma_f32_16x16x32_bf16(Bf[0][ks], af[rf], acc[0][rf], 0, 0, 0);
                acc[1][rf] = __builtin_amdgcn_mfma_f32_16x16x32_bf16(Bf[1][ks], af[rf], acc[1][rf], 0, 0, 0);
            }
        }

        if (more) {
#pragma unroll
            for (int i = (KS - WIN < 0 ? 0 : KS - WIN); i < IST; i++) {
                float4 a0 = gfa[i % WIN], a1 = gfb[i % WIN];
                ssacc += a0.x*a0.x + a0.y*a0.y + a0.z*a0.z + a0.w*a0.w
                       + a1.x*a1.x + a1.y*a1.y + a1.z*a1.z + a1.w*a1.w;
                uint4 pk = { cvt_pk_bf16(a0.x, a0.y), cvt_pk_bf16(a0.z, a0.w),
                             cvt_pk_bf16(a1.x, a1.y), cvt_pk_bf16(a1.z, a1.w) };
                const int slot = ssl0 + 8 * i;
                *(uint4*)(&As[buf ^ 1][srow * P + ((slot ^ (srow & 7)) << 3)]) = pk;
            }
            ssacc += __shfl_xor(ssacc, 1);
            ssacc += __shfl_xor(ssacc, 2);
            ssacc += __shfl_xor(ssacc, 4);
            if (ssl0 == 0) xn2s[buf ^ 1][srow] = ssacc;
        }
        __syncthreads();

#pragma unroll
        for (int rf = 0; rf < 4; rf++) {
            const int row = 16 * rf + l15;
            const float xv = xn2s[buf][row];
            float hs = 0.f, ms = 0.f, gs = 0.f;
#pragma unroll
            for (int j = 0; j < 4; j++) {
                float d2 = xv - 2.f * acc[0][rf][j] + wn2[j];
                float a  = __expf(-g2[j] * d2);
                float ah = a * hv[j];
                hs += ah;
                ms += (acc[1][rf][j] + alv[j]) * ah;
                gs += s2v[j] * ah * ah;
            }
            hs += __shfl_xor(hs, 16); hs += __shfl_xor(hs, 32);
            ms += __shfl_xor(ms, 16); ms += __shfl_xor(ms, 32);
            gs += __shfl_xor(gs, 16); gs += __shfl_xor(gs, 32);
            if (l4 == 0) { part[wv][row][0] = hs; part[wv][row][1] = ms; part[wv][row][2] = gs; }
        }
        __syncthreads();
        if (tid < 192) {
            const int v = tid >> 6, r = tid & 63;
            float sum = 0.f;
#pragma unroll
            for (int w8 = 0; w8 < 8; w8++) sum += part[w8][r][v];
            pws[(size_t)(h * 3 + v) * NT + row0 + r] = sum;
        }
        __syncthreads();
        buf ^= 1;
    }
}

// ======== s1/s2 kernel: R8's depth-3 fused_src VERBATIM (s1+s2 ~18us) ========
// grid 2048, 256 thr (4 waves 2(panel)x2(x)). Block: 128 panel-rows (pt) x 128 x-rows (xt).
// DEPTH-3 PREFETCH: B in 4-deep LDS ring (global_load_lds), x in 4 static reg sets.
#define LGKM0()  asm volatile("s_waitcnt lgkmcnt(0)" ::: "memory")
#define BAR()    __builtin_amdgcn_s_barrier()
#define SB0()    __builtin_amdgcn_sched_barrier(0)

template<int P>
__global__ __launch_bounds__(256, 3)
void fused_small(const float* __restrict__ x, const unsigned short* __restrict__ Bc,
                 const float* __restrict__ prm, float* __restrict__ pwsS) {
    constexpr int NK = P / 32;
    __shared__ unsigned short Bs[4][128 * 32];
    __shared__ unsigned short Xs[2][128 * 32];
    __shared__ float xn2[128];

    const int b = blockIdx.x;
    const int xt = (b >> 5) * 8 + (b & 7);
    const int pt = (b >> 3) & 3;

    const int tid = threadIdx.x, lane = tid & 63, wv = tid >> 6;
    const int wp = wv >> 1, wx = wv & 1;
    const int l15 = lane & 15, l4 = lane >> 4;

    const int srow = tid >> 1, shalf = tid & 1;
    const float* xbase = x + (size_t)(xt * 128 + srow) * P + shalf * 16;

    f32x4 acc[4][4];
#pragma unroll
    for (int pf = 0; pf < 4; pf++)
#pragma unroll
        for (int xf = 0; xf < 4; xf++) acc[pf][xf] = (f32x4){0.f, 0.f, 0.f, 0.f};

    float4 xr[4][4];
    float ss = 0.f;

    auto gloadB = [&](int nb, int t) {
#pragma unroll
        for (int i = 0; i < 2; i++) {
            const int u = i * 256 + tid;
            const int row = u >> 2;
            const int sl = (u & 3) ^ ((row >> 1) & 3);
            const unsigned short* src = Bc + (size_t)(pt * 128 + row) * P + t * 32 + sl * 8;
            __builtin_amdgcn_global_load_lds((const __attribute__((address_space(1))) void*)src,
                (__attribute__((address_space(3))) void*)&Bs[nb][(i * 256 + wv * 64) * 8], 16, 0, 0);
        }
    };
    auto loadX = [&](float4* xrs, int t) {
#pragma unroll
        for (int i = 0; i < 4; i++) xrs[i] = *(const float4*)(xbase + t * 32 + i * 4);
    };
    auto cvtWrite = [&](const float4* xrs, int xb) {
        const int sw = (srow >> 1) & 3;
#pragma unroll
        for (int hh = 0; hh < 2; hh++) {
            float4 q0 = xrs[2 * hh], q1 = xrs[2 * hh + 1];
            ss += q0.x*q0.x + q0.y*q0.y + q0.z*q0.z + q0.w*q0.w
                + q1.x*q1.x + q1.y*q1.y + q1.z*q1.z + q1.w*q1.w;
            uint4 pk = { cvt_pk_bf16(q0.x, q0.y), cvt_pk_bf16(q0.z, q0.w),
                         cvt_pk_bf16(q1.x, q1.y), cvt_pk_bf16(q1.z, q1.w) };
            const int phys = (shalf * 2 + hh) ^ sw;
            *(uint4*)(&Xs[xb][srow * 32 + phys * 8]) = pk;
        }
    };
    auto compute = [&](int bb, int xb) {
        short8 af[4], bf[4];
#pragma unroll
        for (int pf = 0; pf < 4; pf++) {
            const int row = 64 * wp + 16 * pf + l15;
            af[pf] = *(const short8*)(&Bs[bb][row * 32 + ((l4 ^ ((row >> 1) & 3)) << 3)]);
        }
#pragma unroll
        for (int xf = 0; xf < 4; xf++) {
            const int row = 64 * wx + 16 * xf + l15;
            bf[xf] = *(const short8*)(&Xs[xb][row * 32 + ((l4 ^ ((row >> 1) & 3)) << 3)]);
        }
#pragma unroll
        for (int pf = 0; pf < 4; pf++)
#pragma unroll
            for (int xf = 0; xf < 4; xf++)
                acc[pf][xf] = __builtin_amdgcn_mfma_f32_16x16x32_bf16(af[pf], bf[xf], acc[pf][xf], 0, 0, 0);
    };

#pragma unroll
    for (int d = 0; d < 3; d++) {
        if (d < NK) {
            gloadB(d, d); SB0();
            loadX(xr[d], d); SB0();
        }
    }
    cvtWrite(xr[0], 0);
    LGKM0(); SB0(); BAR(); SB0();

#pragma unroll
    for (int t = 0; t < NK; t++) {
        if (t + 3 < NK) {
            gloadB((t + 3) & 3, t + 3); SB0();
            loadX(xr[(t + 3) & 3], t + 3); SB0();
        }
        if (t + 1 < NK) {
            cvtWrite(xr[(t + 1) & 3], (t + 1) & 1);
        }
        LGKM0(); SB0(); BAR(); SB0();
        compute(t & 3, t & 1);
        SB0(); BAR(); SB0();
    }

    ss += __shfl_xor(ss, 1);
    if (shalf == 0) xn2[srow] = ss;
    __syncthreads();

    const int kb0 = (pt * 4 + 2 * wp) * 16 + 4 * l4;
    f32x4 wn2[2], g2[2], hv[2], alv[2], s2v[2];
#pragma unroll
    for (int K = 0; K < 2; K++) {
        const int kk = kb0 + 16 * K;
        wn2[K] = *(const f32x4*)(prm + kk);
        g2[K]  = *(const f32x4*)(prm + 256 + kk);
        hv[K]  = *(const f32x4*)(prm + 512 + kk);
        alv[K] = *(const f32x4*)(prm + 768 + kk);
        s2v[K] = *(const f32x4*)(prm + 1024 + kk);
    }
    float (*part)[128][3] = (float (*)[128][3])(&Bs[0][0]);
#pragma unroll
    for (int xf = 0; xf < 4; xf++) {
        const int xrow = 64 * wx + 16 * xf + l15;
        const float xv = xn2[xrow];
        float hs = 0.f, ms = 0.f, gs = 0.f;
#pragma unroll
        for (int K = 0; K < 2; K++) {
#pragma unroll
            for (int j = 0; j < 4; j++) {
                const float aw = acc[2 * K][xf][j];
                const float ab = acc[2 * K + 1][xf][j];
                const float d2 = xv - 2.f * aw + wn2[K][j];
                const float a  = __expf(-g2[K][j] * d2);
                const float ah = a * hv[K][j];
                hs += ah;
                ms += (ab + alv[K][j]) * ah;
                gs += s2v[K][j] * ah * ah;
            }
        }
        hs += __shfl_xor(hs, 16); hs += __shfl_xor(hs, 32);
        ms += __shfl_xor(ms, 16); ms += __shfl_xor(ms, 32);
        gs += __shfl_xor(gs, 16); gs += __shfl_xor(gs, 32);
        if (l4 == 0) {
            part[wp][xrow][0] = hs;
            part[wp][xrow][1] = ms;
            part[wp][xrow][2] = gs;
        }
    }
    __syncthreads();
    if (tid < 128) {
        const int gr = xt * 128 + tid;
#pragma unroll
        for (int v = 0; v < 3; v++)
            pwsS[(size_t)(pt * 3 + v) * NT + gr] = part[0][tid][v] + part[1][tid][v];
    }
}

// ---------------- combine: s0 from 2-half planes, s1/s2 from 4-pt planes ----------------
__global__ void combine_kernel(const float* __restrict__ pws,
                               const float* __restrict__ d0, const float* __restrict__ d1,
                               const float* __restrict__ d2, float* __restrict__ out) {
    const int t = blockIdx.x * 256 + threadIdx.x;
    float mux[3], s2x[3], hx[3];
    {   // s0: planes 0..5 (h*3+v)
        const float* b = pws;
        const float hh = b[t] + b[(size_t)3 * NT + t];
        const float mm = b[(size_t)1 * NT + t] + b[(size_t)4 * NT + t];
        const float gg = b[(size_t)2 * NT + t] + b[(size_t)5 * NT + t];
        mux[0] = mm / hh; s2x[0] = gg / (hh * hh); hx[0] = hh;
    }
#pragma unroll
    for (int s = 1; s < 3; s++) {   // s1: planes 6..17, s2: planes 18..29 (pt*3+v)
        const float* b = pws + (size_t)(6 + (s - 1) * 12) * NT;
        float hh = 0.f, mm = 0.f, gg = 0.f;
#pragma unroll
        for (int pt = 0; pt < 4; pt++) {
            hh += b[(size_t)(pt * 3 + 0) * NT + t];
            mm += b[(size_t)(pt * 3 + 1) * NT + t];
            gg += b[(size_t)(pt * 3 + 2) * NT + t];
        }
        mux[s] = mm / hh; s2x[s] = gg / (hh * hh); hx[s] = hh;
    }
#pragma unroll
    for (int s = 0; s < 3; s++) {
        out[(size_t)s * NT + t]       = mux[s];
        out[(size_t)(4 + s) * NT + t] = s2x[s];
        out[(size_t)(8 + s) * NT + t] = hx[s];
    }
    const float sd0 = 1.f / (1.f + __expf(-d0[0]));
    const float sd1 = 1.f / (1.f + __expf(-d1[0]));
    const float sd2 = 1.f / (1.f + __expf(-d2[0]));
    const float c0 = hx[0] * sd0, c1 = hx[1] * sd1, c2 = hx[2] * sd2;
    const float den = c0 + c1 + c2;
    const float muc = mux[0] * c0 + mux[1] * c1 + mux[2] * c2;
    const float sgc = s2x[0] * c0 * c0 + s2x[1] * c1 * c1 + s2x[2] * c2 * c2;
    out[(size_t)3 * NT + t]  = muc / den;
    out[(size_t)7 * NT + t]  = sgc / (den * den);
    out[(size_t)11 * NT + t] = den;
}

extern "C" void kernel_launch(void* const* d_in, const int* in_sizes, int n_in,
                              void* d_out, int out_size, void* d_ws, size_t ws_size,
                              hipStream_t stream) {
    // input order per source i: x=8i, alpha=8i+1, beta=8i+2, sig=8i+3, eta=8i+4, gam=8i+5, w=8i+6, disc=8i+7
    const float* x0 = (const float*)d_in[0];
    const float* x1 = (const float*)d_in[8];
    const float* x2 = (const float*)d_in[16];

    unsigned short* bc = (unsigned short*)d_ws;                  // 512*(512+256+128) ushorts = 917504 B
    float* prmAll = (float*)((char*)d_ws + 917504);              // 3*1280 floats = 15360 B
    float* pws    = (float*)((char*)d_ws + 917504 + 15360);      // 30*NT floats = 7.86 MB
    float* out = (float*)d_out;

    prep_kernel<<<1536, 128, 0, stream>>>(
        (const float*)d_in[6],  (const float*)d_in[2],  (const float*)d_in[1],
        (const float*)d_in[3],  (const float*)d_in[4],  (const float*)d_in[5],
        (const float*)d_in[14], (const float*)d_in[10], (const float*)d_in[9],
        (const float*)d_in[11], (const float*)d_in[12], (const float*)d_in[13],
        (const float*)d_in[22], (const float*)d_in[18], (const float*)d_in[17],
        (const float*)d_in[19], (const float*)d_in[20], (const float*)d_in[21],
        bc, prmAll);

    const size_t bcoff1 = 512 * 512, bcoff2 = 512 * 512 + 512 * 256;
    fused_s0<512><<<256, 512, 0, stream>>>(x0, bc, prmAll, pws);
    fused_small<256><<<2048, 256, 0, stream>>>(x1, bc + bcoff1, prmAll + 1280, pws + (size_t)6 * NT);
    fused_small<128><<<2048, 256, 0, stream>>>(x2, bc + bcoff2, prmAll + 2560, pws + (size_t)18 * NT);
    combine_kernel<<<256, 256, 0, stream>>>(pws, (const float*)d_in[7], (const float*)d_in[15],
                                            (const float*)d_in[23], out);
}